// Round 6
// baseline (4189.758 us; speedup 1.0000x reference)
//
#include <hip/hip_runtime.h>

// GRU persistent-scan kernel for MI355X (gfx950). Round 6.
// B=128, T=512, I=256, H=512. Global I/O f32; GEMMs bf16 MFMA, f32 accum.
//
// 8 clusters (16 batch rows) x 8 WGs x 256 threads (4 waves). WG w owns H
// cols [64w,64w+64); wave s owns [64w+16s,+16) fully. Weights in registers.
//
// Exchange protocol (round 6): SELF-VALIDATING TAGGED WORDS. Each exchanged
// bf16 value is published as u32 (epoch<<16)|bf16 via relaxed agent-scope
// atomics (L2-bypass, meet at L3). Readers poll the data words directly and
// accept a chunk when all 8 tags == epoch — no flags, no vmcnt-drain-before-
// flag, no separate observe RTT: ~1 L3 round trip per hop. Epochs are
// monotonic (h: t+1, rh: t+1); overtake is impossible because h(t+2) publish
// is gated on rh(t+1) which is gated on all WGs consuming h(t+1). 0xAA ws
// poison cannot forge a tag in [1,513], so no memset is needed.

typedef __attribute__((ext_vector_type(8))) short bf16x8;
typedef __attribute__((ext_vector_type(4))) float f32x4;
typedef unsigned short u16;
typedef unsigned int u32;
typedef unsigned long long u64;

#define B_ 128
#define T_ 512
#define I_ 256
#define H_ 512

__device__ __forceinline__ u16 f2b(float f) {
  union { float f; u32 i; } v; v.f = f;
  u32 u = v.i;
  return (u16)((u + 0x7FFFu + ((u >> 16) & 1u)) >> 16);  // RNE
}

__device__ __forceinline__ u64 aload(u64* p) {
  return __hip_atomic_load(p, __ATOMIC_RELAXED, __HIP_MEMORY_SCOPE_AGENT);
}
__device__ __forceinline__ void astore(u64* p, u64 v) {
  __hip_atomic_store(p, v, __ATOMIC_RELAXED, __HIP_MEMORY_SCOPE_AGENT);
}

// prep: convert 6 weight tensors f32 -> bf16 into ws
// layout: Rz[512x512], Rr, Rh, Wz[512x256], Wr, Wh; row-major [out][in]
__global__ void prep_weights(const float* __restrict__ rz, const float* __restrict__ rr,
                             const float* __restrict__ rh, const float* __restrict__ wz,
                             const float* __restrict__ wr, const float* __restrict__ wh,
                             u16* __restrict__ wout) {
  int idx = blockIdx.x * 256 + threadIdx.x;
  if (idx >= 1179648) return;
  float v;
  if (idx < 262144)       v = rz[idx];
  else if (idx < 524288)  v = rr[idx - 262144];
  else if (idx < 786432)  v = rh[idx - 524288];
  else if (idx < 917504)  v = wz[idx - 786432];
  else if (idx < 1048576) v = wr[idx - 917504];
  else                    v = wh[idx - 1048576];
  wout[idx] = f2b(v);
}

// Gather one 16x512 tagged panel into swizzled bf16 LDS. Issues all 16 u64
// loads first (pipelined), then validates per-chunk, re-loading only stale.
__device__ __forceinline__ void gather_panel(u64* __restrict__ buf, int b0, int tid,
                                             u32 tg, u16* __restrict__ dst) {
  u64 qd[16];
  u64* pA[4];
  int rowA[4], kcA[4];
#pragma unroll
  for (int it = 0; it < 4; ++it) {
    int id  = it * 256 + tid;            // 1024 chunks of 8 tagged u32
    int row = id >> 6, kc = id & 63;
    rowA[it] = row; kcA[it] = kc;
    u64* p = buf + (((b0 + row) * H_ + kc * 8) >> 1);
    pA[it] = p;
    qd[it * 4 + 0] = aload(p);
    qd[it * 4 + 1] = aload(p + 1);
    qd[it * 4 + 2] = aload(p + 2);
    qd[it * 4 + 3] = aload(p + 3);
  }
#pragma unroll
  for (int it = 0; it < 4; ++it) {
    for (;;) {
      bool ok = true;
#pragma unroll
      for (int k2 = 0; k2 < 4; ++k2) {
        u64 v = qd[it * 4 + k2];
        ok &= (((v >> 16) & 0xFFFFu) == tg) & ((u32)(v >> 48) == tg);
      }
      if (__builtin_expect(ok, 1)) break;
#pragma unroll
      for (int k2 = 0; k2 < 4; ++k2) qd[it * 4 + k2] = aload(pA[it] + k2);
    }
    union { u32 w[4]; bf16x8 v; } pk;
#pragma unroll
    for (int k2 = 0; k2 < 4; ++k2) {
      u64 v = qd[it * 4 + k2];
      pk.w[k2] = (u32)(v & 0xFFFFu) | ((u32)((v >> 32) & 0xFFFFu) << 16);
    }
    *(bf16x8*)&dst[rowA[it] * 512 + (kcA[it] ^ (rowA[it] & 7)) * 8] = pk.v;
  }
}

__global__ __launch_bounds__(256, 1) void gru_persist(
    const float* __restrict__ x, const float* __restrict__ h0,
    const u16* __restrict__ wsW,
    const float* __restrict__ bwz, const float* __restrict__ bwr, const float* __restrict__ bwh,
    const float* __restrict__ brz, const float* __restrict__ brr, const float* __restrict__ brh,
    float* __restrict__ out, u64* __restrict__ hbt, u64* __restrict__ rhbt)
{
  const int tid  = threadIdx.x;
  const int wv   = tid >> 6;        // wave 0..3
  const int lane = tid & 63;
  const int n    = lane & 15;       // MFMA A-row m == B-col n == C col
  const int q    = lane >> 4;       // quad; A/B k-chunk q*8; C rows 4q..4q+3
  const int c    = blockIdx.x >> 3; // cluster 0..7
  const int w    = blockIdx.x & 7;  // WG-in-cluster (H-slice)
  const int nj   = w * 64 + wv * 16 + n;  // global H column
  const int b0   = c * 16;                // batch base row

  const u16* wrz = wsW;             // [512][512]
  const u16* wrr = wsW + 262144;
  const u16* wrh = wsW + 524288;
  const u16* wwz = wsW + 786432;    // [512][256]
  const u16* wwr = wsW + 917504;
  const u16* wwh = wsW + 1048576;

  // LDS ~44 KB
  __shared__ __align__(16) u16 sA[16 * 512];  // h panel (bf16)
  __shared__ __align__(16) u16 sB[16 * 512];  // rh panel (bf16)
  __shared__ __align__(16) u16 sX[16 * 256];  // x_t panel (bf16)
  __shared__ __align__(16) u32 sT[4 * 256];   // per-wave tagged publish tiles

  // ---- preload ALL weight fragments for this lane's column into registers
  bf16x8 rzf[16], rrf[16], rhf[16], wzf[8], wrf[8], whf[8];
#pragma unroll
  for (int kb = 0; kb < 16; ++kb) {
    rzf[kb] = *(const bf16x8*)&wrz[nj * H_ + kb * 32 + q * 8];
    rrf[kb] = *(const bf16x8*)&wrr[nj * H_ + kb * 32 + q * 8];
    rhf[kb] = *(const bf16x8*)&wrh[nj * H_ + kb * 32 + q * 8];
  }
#pragma unroll
  for (int kb = 0; kb < 8; ++kb) {
    wzf[kb] = *(const bf16x8*)&wwz[nj * I_ + kb * 32 + q * 8];
    wrf[kb] = *(const bf16x8*)&wwr[nj * I_ + kb * 32 + q * 8];
    whf[kb] = *(const bf16x8*)&wwh[nj * I_ + kb * 32 + q * 8];
  }

  const float bz  = bwz[nj] + brz[nj];
  const float brg = bwr[nj] + brr[nj];
  const float bhg = bwh[nj] + brh[nj];

  float hold[4];
#pragma unroll
  for (int i = 0; i < 4; ++i) hold[i] = h0[(b0 + q * 4 + i) * H_ + nj];

  // publish geometry: lane handles 4 consecutive u32 of its wave tile
  const int prow = lane >> 2, pc0 = (lane & 3) * 4;
  const int pub64 = (((b0 + prow) * H_ + w * 64 + wv * 16 + pc0) >> 1);
  u32* sTw = &sT[wv * 256];

  // ---- initial publish of h(0) = h0, tag 1
  {
#pragma unroll
    for (int i = 0; i < 4; ++i)
      sTw[(q * 4 + i) * 16 + n] = (1u << 16) | (u32)f2b(hold[i]);
    __threadfence_block();
    astore(&hbt[pub64],     *(const u64*)&sTw[prow * 16 + pc0]);
    astore(&hbt[pub64 + 1], *(const u64*)&sTw[prow * 16 + pc0 + 2]);
  }

  for (int t = 0; t < T_; ++t) {
    const u32 tg = (u32)(t + 1);
    __syncthreads();  // protects sA/sB/sX/sT reuse across steps

    // ---- stage x_t panel (f32 -> bf16); loads overlap the h-hop
#pragma unroll
    for (int it = 0; it < 2; ++it) {
      int id = it * 256 + tid;
      int row = id >> 5, kc = id & 31;
      const float* src = &x[(b0 + row) * (T_ * I_) + t * I_ + kc * 8];
      float4 v0 = *(const float4*)src;
      float4 v1 = *(const float4*)(src + 4);
      union { u16 u[8]; bf16x8 v; } pk;
      pk.u[0] = f2b(v0.x); pk.u[1] = f2b(v0.y); pk.u[2] = f2b(v0.z); pk.u[3] = f2b(v0.w);
      pk.u[4] = f2b(v1.x); pk.u[5] = f2b(v1.y); pk.u[6] = f2b(v1.z); pk.u[7] = f2b(v1.w);
      *(bf16x8*)&sX[row * 256 + (kc ^ (row & 7)) * 8] = pk.v;
    }

    // ---- h(t) hop: poll tagged data, pack into sA
    gather_panel(hbt, b0, tid, tg, sA);
    __syncthreads();

    // ---- z & r gates (wave-local 16 cols; shared A-frag for both gates)
    f32x4 az0 = {0.f,0.f,0.f,0.f}, az1 = {0.f,0.f,0.f,0.f};
    f32x4 ar0 = {0.f,0.f,0.f,0.f}, ar1 = {0.f,0.f,0.f,0.f};
#pragma unroll
    for (int kb = 0; kb < 16; kb += 2) {
      bf16x8 a0 = *(const bf16x8*)&sA[n * 512 + ((kb * 4 + q) ^ (n & 7)) * 8];
      az0 = __builtin_amdgcn_mfma_f32_16x16x32_bf16(a0, rzf[kb], az0, 0, 0, 0);
      ar0 = __builtin_amdgcn_mfma_f32_16x16x32_bf16(a0, rrf[kb], ar0, 0, 0, 0);
      bf16x8 a1 = *(const bf16x8*)&sA[n * 512 + (((kb + 1) * 4 + q) ^ (n & 7)) * 8];
      az1 = __builtin_amdgcn_mfma_f32_16x16x32_bf16(a1, rzf[kb + 1], az1, 0, 0, 0);
      ar1 = __builtin_amdgcn_mfma_f32_16x16x32_bf16(a1, rrf[kb + 1], ar1, 0, 0, 0);
    }
#pragma unroll
    for (int kb = 0; kb < 8; kb += 2) {
      bf16x8 a0 = *(const bf16x8*)&sX[n * 256 + ((kb * 4 + q) ^ (n & 7)) * 8];
      az0 = __builtin_amdgcn_mfma_f32_16x16x32_bf16(a0, wzf[kb], az0, 0, 0, 0);
      ar0 = __builtin_amdgcn_mfma_f32_16x16x32_bf16(a0, wrf[kb], ar0, 0, 0, 0);
      bf16x8 a1 = *(const bf16x8*)&sX[n * 256 + (((kb + 1) * 4 + q) ^ (n & 7)) * 8];
      az1 = __builtin_amdgcn_mfma_f32_16x16x32_bf16(a1, wzf[kb + 1], az1, 0, 0, 0);
      ar1 = __builtin_amdgcn_mfma_f32_16x16x32_bf16(a1, wrf[kb + 1], ar1, 0, 0, 0);
    }

    float zreg[4];
#pragma unroll
    for (int i = 0; i < 4; ++i) {
      zreg[i] = 1.f / (1.f + __expf(-(az0[i] + az1[i] + bz)));
      float rv = 1.f / (1.f + __expf(-(ar0[i] + ar1[i] + brg)));
      sTw[(q * 4 + i) * 16 + n] = (tg << 16) | (u32)f2b(rv * hold[i]);
    }
    __threadfence_block();
    astore(&rhbt[pub64],     *(const u64*)&sTw[prow * 16 + pc0]);
    astore(&rhbt[pub64 + 1], *(const u64*)&sTw[prow * 16 + pc0 + 2]);

    // ---- hh x-part while the rh hop is in flight
    f32x4 ah0 = {0.f,0.f,0.f,0.f}, ah1 = {0.f,0.f,0.f,0.f};
#pragma unroll
    for (int kb = 0; kb < 8; kb += 2) {
      bf16x8 a0 = *(const bf16x8*)&sX[n * 256 + ((kb * 4 + q) ^ (n & 7)) * 8];
      ah0 = __builtin_amdgcn_mfma_f32_16x16x32_bf16(a0, whf[kb], ah0, 0, 0, 0);
      bf16x8 a1 = *(const bf16x8*)&sX[n * 256 + (((kb + 1) * 4 + q) ^ (n & 7)) * 8];
      ah1 = __builtin_amdgcn_mfma_f32_16x16x32_bf16(a1, whf[kb + 1], ah1, 0, 0, 0);
    }

    // ---- rh(t) hop: poll tagged data, pack into sB
    gather_panel(rhbt, b0, tid, tg, sB);
    __syncthreads();

    // ---- hh recurrent part
#pragma unroll
    for (int kb = 0; kb < 16; kb += 2) {
      bf16x8 a0 = *(const bf16x8*)&sB[n * 512 + ((kb * 4 + q) ^ (n & 7)) * 8];
      ah0 = __builtin_amdgcn_mfma_f32_16x16x32_bf16(a0, rhf[kb], ah0, 0, 0, 0);
      bf16x8 a1 = *(const bf16x8*)&sB[n * 512 + (((kb + 1) * 4 + q) ^ (n & 7)) * 8];
      ah1 = __builtin_amdgcn_mfma_f32_16x16x32_bf16(a1, rhf[kb + 1], ah1, 0, 0, 0);
    }

    // ---- epilogue: h' = (1-z)*tanh(.) + z*h ; publish h(t+1) FIRST, then out
    float hn4[4];
#pragma unroll
    for (int i = 0; i < 4; ++i) {
      float hhv = tanhf(ah0[i] + ah1[i] + bhg);
      float hn  = (1.f - zreg[i]) * hhv + zreg[i] * hold[i];
      hold[i] = hn; hn4[i] = hn;
      sTw[(q * 4 + i) * 16 + n] = ((tg + 1u) << 16) | (u32)f2b(hn);
    }
    __threadfence_block();
    astore(&hbt[pub64],     *(const u64*)&sTw[prow * 16 + pc0]);
    astore(&hbt[pub64 + 1], *(const u64*)&sTw[prow * 16 + pc0 + 2]);
#pragma unroll
    for (int i = 0; i < 4; ++i) {
      out[(b0 + q * 4 + i) * (T_ * H_) + t * H_ + nj] = hn4[i];
      if (t == T_ - 1) out[B_ * T_ * H_ + (b0 + q * 4 + i) * H_ + nj] = hn4[i];
    }
  }
}

extern "C" void kernel_launch(void* const* d_in, const int* in_sizes, int n_in,
                              void* d_out, int out_size, void* d_ws, size_t ws_size,
                              hipStream_t stream) {
  const float* xp   = (const float*)d_in[0];
  const float* h0p  = (const float*)d_in[1];
  const float* wzp  = (const float*)d_in[2];
  const float* wrp  = (const float*)d_in[3];
  const float* whp  = (const float*)d_in[4];
  const float* rzp  = (const float*)d_in[5];
  const float* rrp  = (const float*)d_in[6];
  const float* rhp  = (const float*)d_in[7];
  const float* bwzp = (const float*)d_in[8];
  const float* bwrp = (const float*)d_in[9];
  const float* bwhp = (const float*)d_in[10];
  const float* brzp = (const float*)d_in[11];
  const float* brrp = (const float*)d_in[12];
  const float* brhp = (const float*)d_in[13];

  unsigned char* ws = (unsigned char*)d_ws;
  u16* wsW  = (u16*)(ws);            // 1,179,648 bf16 weights (2,359,296 B)
  u64* hbt  = (u64*)(ws + 2359296);  // [B][H] tagged u32 h      (262,144 B)
  u64* rhbt = (u64*)(ws + 2621440);  // [B][H] tagged u32 r*h    (262,144 B)

  prep_weights<<<dim3(4608), dim3(256), 0, stream>>>(rzp, rrp, rhp, wzp, wrp, whp, wsW);

  gru_persist<<<dim3(64), dim3(256), 0, stream>>>(
      xp, h0p, wsW,
      bwzp, bwrp, bwhp, brzp, brrp, brhp,
      (float*)d_out, hbt, rhbt);
}